// Round 4
// baseline (480.127 us; speedup 1.0000x reference)
//
#include <hip/hip_runtime.h>

#define NN 100000
#define NE 1600000
#define NBLK_SCAN ((NN + 1023) / 1024)   // 98 blocks of 1024 elems

// Radix partition params: buckets of 256 nodes
#define K_B 391                          // ceil(NN/256) buckets
#define B_P 256                          // partition blocks
#define CH  ((NE + B_P - 1) / B_P)       // 6250 edges per partition block
#define NSC (K_B * B_P)                  // histogram table size (100096)
#define SEG ((NSC + 1023) / 1024)        // elems per thread in hist scan (98)

// ---------------------------------------------------------------------------
// edge_index dtype detection: if int64 (values < 2^31), odd 32-bit words are 0.
// For int32 data the odd words are random edge indices (nonzero w.h.p.).
__global__ void k_detect(const unsigned int* w, int* flag) {
    int i = blockIdx.x * blockDim.x + threadIdx.x;
    if (i < 65536 && w[2 * i + 1] != 0u) *flag = 1;
}

__device__ __forceinline__ void load_edge(const void* ei, int is32, int e,
                                          int& s, int& d) {
    if (is32) {
        const int* p = (const int*)ei;
        s = p[e]; d = p[NE + e];
    } else {
        const long long* p = (const long long*)ei;
        s = (int)p[e]; d = (int)p[NE + e];
    }
}

// ---------------------------------------------------------------------------
// P1: per-block histogram of dst>>8 over this block's edge chunk
__global__ __launch_bounds__(256) void k_hist(const void* ei, const int* __restrict__ flag,
                                              int* __restrict__ hist) {
    __shared__ int h[K_B];
    for (int i = threadIdx.x; i < K_B; i += 256) h[i] = 0;
    __syncthreads();
    int b = blockIdx.x;
    int is32 = *flag;
    int e0 = b * CH, e1 = min(e0 + CH, NE);
    for (int e = e0 + threadIdx.x; e < e1; e += 256) {
        int d = is32 ? ((const int*)ei)[NE + e] : (int)((const long long*)ei)[NE + e];
        atomicAdd(&h[d >> 8], 1);
    }
    __syncthreads();
    for (int i = threadIdx.x; i < K_B; i += 256) hist[i * B_P + b] = h[i];
}

// P2: single-block in-place exclusive scan of hist[NSC] (bucket-major)
__global__ __launch_bounds__(1024) void k_scanhist(int* hist) {
    __shared__ int lds[1024];
    int t = threadIdx.x;
    int base = t * SEG;
    int sum = 0;
    for (int i = 0; i < SEG; ++i) {
        int idx = base + i;
        if (idx < NSC) sum += hist[idx];
    }
    lds[t] = sum;
    __syncthreads();
    for (int off = 1; off < 1024; off <<= 1) {
        int v = (t >= off) ? lds[t - off] : 0;
        __syncthreads();
        lds[t] += v;
        __syncthreads();
    }
    int run = lds[t] - sum;  // exclusive prefix of this thread's segment
    for (int i = 0; i < SEG; ++i) {
        int idx = base + i;
        if (idx < NSC) { int v = hist[idx]; hist[idx] = run; run += v; }
    }
}

// P3: partition edges into per-(block,bucket) contiguous runs (LDS cursors only)
__global__ __launch_bounds__(256) void k_part(const void* ei, const int* __restrict__ flag,
                                              const int* __restrict__ off,
                                              unsigned* __restrict__ packed) {
    __shared__ int cur[K_B];
    int b = blockIdx.x;
    for (int i = threadIdx.x; i < K_B; i += 256) cur[i] = off[i * B_P + b];
    __syncthreads();
    int is32 = *flag;
    int e0 = b * CH, e1 = min(e0 + CH, NE);
    for (int e = e0 + threadIdx.x; e < e1; e += 256) {
        int s, d;
        load_edge(ei, is32, e, s, d);
        int k = d >> 8;
        int pos = atomicAdd(&cur[k], 1);
        packed[pos] = ((unsigned)s << 8) | (unsigned)(d & 255);
    }
}

// P4a: per-bucket count -> deg (non-atomic global write; each node owned by 1 block)
__global__ __launch_bounds__(256) void k_hist2(const int* __restrict__ off,
                                               const unsigned* __restrict__ packed,
                                               int* __restrict__ deg) {
    __shared__ int cnt[256];
    int k = blockIdx.x;
    cnt[threadIdx.x] = 0;
    __syncthreads();
    int g0 = off[k * B_P];
    int g1 = (k == K_B - 1) ? NE : off[(k + 1) * B_P];
    for (int i = g0 + threadIdx.x; i < g1; i += 256)
        atomicAdd(&cnt[packed[i] & 255u], 1);
    __syncthreads();
    int n = (k << 8) + threadIdx.x;
    if (n < NN) deg[n] = cnt[threadIdx.x];
}

// P4b: per-bucket counting place -> ssrc in CSR (dst-sorted) order
__global__ __launch_bounds__(256) void k_place(const int* __restrict__ off,
                                               const int* __restrict__ rowptr,
                                               const unsigned* __restrict__ packed,
                                               int* __restrict__ ssrc) {
    __shared__ int rbase[256];
    __shared__ int cnt[256];
    int k = blockIdx.x;
    int n = (k << 8) + threadIdx.x;
    rbase[threadIdx.x] = (n < NN) ? rowptr[n] : 0;
    cnt[threadIdx.x] = 0;
    __syncthreads();
    int g0 = off[k * B_P];
    int g1 = (k == K_B - 1) ? NE : off[(k + 1) * B_P];
    for (int i = g0 + threadIdx.x; i < g1; i += 256) {
        unsigned pk = packed[i];
        int dl = pk & 255u;
        int s = (int)(pk >> 8);
        int r = atomicAdd(&cnt[dl], 1);
        ssrc[rbase[dl] + r] = s;
    }
}

// ---------------------------------------------------------------------------
// Exclusive scan of deg -> rowptr (3 kernels)
__global__ __launch_bounds__(256) void k_scan1(const int* __restrict__ deg,
                                               int* __restrict__ ex,
                                               int* __restrict__ bsum) {
    __shared__ int lds[256];
    int b = blockIdx.x, t = threadIdx.x;
    int base = b * 1024 + t * 4;
    int v[4];
#pragma unroll
    for (int k = 0; k < 4; ++k) { int i = base + k; v[k] = (i < NN) ? deg[i] : 0; }
    int s = v[0] + v[1] + v[2] + v[3];
    lds[t] = s;
    __syncthreads();
    for (int off = 1; off < 256; off <<= 1) {
        int tmp = (t >= off) ? lds[t - off] : 0;
        __syncthreads();
        lds[t] += tmp;
        __syncthreads();
    }
    int run = lds[t] - s;
#pragma unroll
    for (int k = 0; k < 4; ++k) {
        int i = base + k;
        if (i < NN) ex[i] = run;
        run += v[k];
    }
    if (t == 255) bsum[b] = lds[255];
}

__global__ __launch_bounds__(128) void k_scan2(int* bsum) {
    __shared__ int lds[128];
    int t = threadIdx.x;
    int v = (t < NBLK_SCAN) ? bsum[t] : 0;
    lds[t] = v;
    __syncthreads();
    for (int off = 1; off < 128; off <<= 1) {
        int tmp = (t >= off) ? lds[t - off] : 0;
        __syncthreads();
        lds[t] += tmp;
        __syncthreads();
    }
    if (t < NBLK_SCAN) bsum[t] = lds[t] - v;  // exclusive
}

// rowptr + dinv + normalized x (xn = dinv * x) in one pass
__global__ void k_scan3(const int* __restrict__ ex, const int* __restrict__ bsum,
                        const int* __restrict__ deg, const float* __restrict__ x,
                        int* __restrict__ rowptr, float* __restrict__ dinv,
                        float2* __restrict__ xn) {
    int i = blockIdx.x * blockDim.x + threadIdx.x;
    if (i < NN) {
        rowptr[i] = ex[i] + bsum[i >> 10];
        float di = rsqrtf((float)(deg[i] + 1));  // +1 self-loop
        dinv[i] = di;
        float2 xv = ((const float2*)x)[i];
        xn[i] = make_float2(xv.x * di, xv.y * di);
    }
    if (i == 0) rowptr[NN] = NE;
}

// ---------------------------------------------------------------------------
// Layer 1 fused: agg of xn (2-wide) + 2->64 transform + bias + ReLU.
__global__ __launch_bounds__(256) void k_layer1(const int* __restrict__ rowptr,
                                                const int* __restrict__ ssrc,
                                                const float2* __restrict__ xn,
                                                const float* __restrict__ dinv,
                                                const float* __restrict__ W1,
                                                const float* __restrict__ b1,
                                                float* __restrict__ h) {
    int node = blockIdx.x * 4 + (threadIdx.x >> 6);
    if (node >= NN) return;
    int lane = threadIdx.x & 63;
    float2 a = xn[node];  // self loop
    float ax = a.x, ay = a.y;
    int s0 = rowptr[node], e0 = rowptr[node + 1];
    int i = s0;
    for (; i + 2 <= e0; i += 2) {
        float2 v0 = xn[ssrc[i]];
        float2 v1 = xn[ssrc[i + 1]];
        ax += v0.x + v1.x;
        ay += v0.y + v1.y;
    }
    for (; i < e0; ++i) { float2 v = xn[ssrc[i]]; ax += v.x; ay += v.y; }
    float di = dinv[node];
    ax *= di; ay *= di;
    float v = fmaf(ax, W1[lane], fmaf(ay, W1[64 + lane], b1[lane]));
    h[(size_t)node * 64 + lane] = fmaxf(v, 0.f);
}

// 64x64 GEMM transform: t[n][:] = dinv[n] * (h[n][:] @ W)
__global__ __launch_bounds__(256) void k_gemm64(const float* __restrict__ h,
                                                const float* __restrict__ W,
                                                const float* __restrict__ dinv,
                                                float* __restrict__ t) {
    __shared__ float Ws[64 * 64];
    __shared__ float hs[4][64];
    int tx = threadIdx.x & 63, ty = threadIdx.x >> 6;
    for (int i = threadIdx.x; i < 64 * 64; i += 256) Ws[i] = W[i];
    __syncthreads();
    int base = blockIdx.x * 64;
    for (int it = 0; it < 16; ++it) {
        int n = base + it * 4 + ty;
        if (n < NN) hs[ty][tx] = h[(size_t)n * 64 + tx];
        __syncthreads();
        if (n < NN) {
            float acc = 0.f;
#pragma unroll
            for (int k = 0; k < 64; ++k) acc += hs[ty][k] * Ws[k * 64 + tx];
            t[(size_t)n * 64 + tx] = dinv[n] * acc;
        }
        __syncthreads();
    }
}

// 64->1 transform: t3[n] = dinv[n] * dot(h[n][:], W3)
__global__ void k_transform3(const float* __restrict__ h, const float* __restrict__ W3,
                             const float* __restrict__ dinv, float* __restrict__ t3) {
    int tid = blockIdx.x * blockDim.x + threadIdx.x;
    if (tid >= NN * 64) return;
    int n = tid >> 6, k = tid & 63;
    float v = h[(size_t)n * 64 + k] * W3[k];
#pragma unroll
    for (int off = 32; off > 0; off >>= 1) v += __shfl_down(v, off, 64);
    if (k == 0) t3[n] = dinv[n] * v;
}

// ---------------------------------------------------------------------------
// Pull aggregation (64-wide), fused finalize: one 64-lane wave per node.
__global__ __launch_bounds__(256) void k_aggregate(const int* __restrict__ rowptr,
                                                   const int* __restrict__ ssrc,
                                                   const float* __restrict__ t,
                                                   const float* __restrict__ dinv,
                                                   const float* __restrict__ b,
                                                   float* __restrict__ hout, int relu) {
    int node = blockIdx.x * 4 + (threadIdx.x >> 6);
    if (node >= NN) return;
    int lane = threadIdx.x & 63;
    int start = rowptr[node], end = rowptr[node + 1];
    float acc = t[(size_t)node * 64 + lane];  // self loop
    int i = start;
    for (; i + 4 <= end; i += 4) {
        int s0 = ssrc[i], s1 = ssrc[i + 1], s2 = ssrc[i + 2], s3 = ssrc[i + 3];
        float a0 = t[(size_t)s0 * 64 + lane];
        float a1 = t[(size_t)s1 * 64 + lane];
        float a2 = t[(size_t)s2 * 64 + lane];
        float a3 = t[(size_t)s3 * 64 + lane];
        acc += a0 + a1 + a2 + a3;
    }
    for (; i < end; ++i) acc += t[(size_t)ssrc[i] * 64 + lane];
    float v = dinv[node] * acc + b[lane];
    if (relu) v = fmaxf(v, 0.f);
    hout[(size_t)node * 64 + lane] = v;
}

// Scalar variant for the 1-wide last layer: one thread per node.
__global__ void k_aggregate3(const int* __restrict__ rowptr, const int* __restrict__ ssrc,
                             const float* __restrict__ t3, const float* __restrict__ dinv,
                             const float* __restrict__ b3, float* __restrict__ out) {
    int n = blockIdx.x * blockDim.x + threadIdx.x;
    if (n >= NN) return;
    int s = rowptr[n], e = rowptr[n + 1];
    float acc = t3[n];
    int i = s;
    for (; i + 4 <= e; i += 4)
        acc += t3[ssrc[i]] + t3[ssrc[i + 1]] + t3[ssrc[i + 2]] + t3[ssrc[i + 3]];
    for (; i < e; ++i) acc += t3[ssrc[i]];
    out[n] = dinv[n] * acc + b3[0];
}

// ---------------------------------------------------------------------------
extern "C" void kernel_launch(void* const* d_in, const int* in_sizes, int n_in,
                              void* d_out, int out_size, void* d_ws, size_t ws_size,
                              hipStream_t stream) {
    const float* x  = (const float*)d_in[0];
    const void*  ei = d_in[1];
    const float* W1 = (const float*)d_in[2];
    const float* b1 = (const float*)d_in[3];
    const float* W2 = (const float*)d_in[4];
    const float* b2 = (const float*)d_in[5];
    const float* W3 = (const float*)d_in[6];
    const float* b3 = (const float*)d_in[7];
    float* out = (float*)d_out;

    char* ws = (char*)d_ws;
    size_t off_b = 0;
    auto take = [&](size_t bytes) -> char* {
        char* p = ws + off_b;
        off_b = (off_b + bytes + 255) & ~(size_t)255;
        return p;
    };
    float*    dinv   = (float*)take((size_t)NN * 4);
    int*      deg    = (int*)take((size_t)NN * 4);
    int*      flag   = (int*)take(4);
    int*      ex     = (int*)take((size_t)NN * 4);
    int*      bsum   = (int*)take(128 * 4);
    int*      rowptr = (int*)take((size_t)(NN + 1) * 4);
    int*      hist   = (int*)take((size_t)NSC * 4);
    unsigned* packed = (unsigned*)take((size_t)NE * 4);
    int*      ssrc   = (int*)take((size_t)NE * 4);
    float2*   xn     = (float2*)take((size_t)NN * 8);
    float*    tb     = (float*)take((size_t)NN * 64 * 4);
    float*    hb     = (float*)take((size_t)NN * 64 * 4);
    float*    t3     = (float*)take((size_t)NN * 4);

    // --- edge dtype detect ---
    hipMemsetAsync(flag, 0, 4, stream);
    k_detect<<<256, 256, 0, stream>>>((const unsigned int*)ei, flag);

    // --- atomic-free radix partition by dst (coarse buckets of 256 nodes) ---
    k_hist<<<B_P, 256, 0, stream>>>(ei, flag, hist);
    k_scanhist<<<1, 1024, 0, stream>>>(hist);
    k_part<<<B_P, 256, 0, stream>>>(ei, flag, hist, packed);
    k_hist2<<<K_B, 256, 0, stream>>>(hist, packed, deg);

    // --- rowptr scan + dinv + xn ---
    k_scan1<<<NBLK_SCAN, 256, 0, stream>>>(deg, ex, bsum);
    k_scan2<<<1, 128, 0, stream>>>(bsum);
    k_scan3<<<(NN + 255) / 256, 256, 0, stream>>>(ex, bsum, deg, x, rowptr, dinv, xn);

    // --- fine place into CSR order ---
    k_place<<<K_B, 256, 0, stream>>>(hist, rowptr, packed, ssrc);

    const int nblk_agg = (NN + 3) / 4;  // 4 waves (nodes) per block
    const int nblk_nf  = (NN * 64 + 255) / 256;

    // --- layer 1 (fused 2-wide aggregate + transform) ---
    k_layer1<<<nblk_agg, 256, 0, stream>>>(rowptr, ssrc, xn, dinv, W1, b1, hb);

    // --- layer 2 ---
    k_gemm64<<<(NN + 63) / 64, 256, 0, stream>>>(hb, W2, dinv, tb);
    k_aggregate<<<nblk_agg, 256, 0, stream>>>(rowptr, ssrc, tb, dinv, b2, hb, 1);

    // --- layer 3 ---
    k_transform3<<<nblk_nf, 256, 0, stream>>>(hb, W3, dinv, t3);
    k_aggregate3<<<(NN + 255) / 256, 256, 0, stream>>>(rowptr, ssrc, t3, dinv, b3, out);
}

// Round 5
// 285.747 us; speedup vs baseline: 1.6803x; 1.6803x over previous
//
#include <hip/hip_runtime.h>

#define NN 100000
#define NE 1600000

// Radix partition params: buckets of 256 nodes
#define K_B 391                          // ceil(NN/256) buckets
#define B_P 256                          // partition blocks
#define CH  ((NE + B_P - 1) / B_P)       // 6250 edges per partition block
#define NSC (K_B * B_P)                  // histogram table size (100096)
#define NBLK_H ((NSC + 1023) / 1024)     // 98 blocks for hist scan

// ---------------------------------------------------------------------------
// edge_index dtype detection: if int64 (values < 2^31), odd 32-bit words are 0.
__global__ void k_detect(const unsigned int* w, int* flag) {
    int i = blockIdx.x * blockDim.x + threadIdx.x;
    if (i < 65536 && w[2 * i + 1] != 0u) *flag = 1;
}

__device__ __forceinline__ void load_edge(const void* ei, int is32, int e,
                                          int& s, int& d) {
    if (is32) {
        const int* p = (const int*)ei;
        s = p[e]; d = p[NE + e];
    } else {
        const long long* p = (const long long*)ei;
        s = (int)p[e]; d = (int)p[NE + e];
    }
}

// ---------------------------------------------------------------------------
// P1: per-block histogram of dst>>8 over this block's edge chunk
__global__ __launch_bounds__(256) void k_hist(const void* ei, const int* __restrict__ flag,
                                              int* __restrict__ hist) {
    __shared__ int h[K_B];
    for (int i = threadIdx.x; i < K_B; i += 256) h[i] = 0;
    __syncthreads();
    int b = blockIdx.x;
    int is32 = *flag;
    int e0 = b * CH, e1 = min(e0 + CH, NE);
    for (int e = e0 + threadIdx.x; e < e1; e += 256) {
        int d = is32 ? ((const int*)ei)[NE + e] : (int)((const long long*)ei)[NE + e];
        atomicAdd(&h[d >> 8], 1);
    }
    __syncthreads();
    for (int i = threadIdx.x; i < K_B; i += 256) hist[i * B_P + b] = h[i];
}

// ---------------------------------------------------------------------------
// Generalized hierarchical exclusive scan (3 kernels), n <= 128*1024
__global__ __launch_bounds__(256) void k_gscan1(const int* __restrict__ in,
                                                int* __restrict__ ex,
                                                int* __restrict__ bsum, int n) {
    __shared__ int lds[256];
    int b = blockIdx.x, t = threadIdx.x;
    int base = b * 1024 + t * 4;
    int v[4];
#pragma unroll
    for (int k = 0; k < 4; ++k) { int i = base + k; v[k] = (i < n) ? in[i] : 0; }
    int s = v[0] + v[1] + v[2] + v[3];
    lds[t] = s;
    __syncthreads();
    for (int off = 1; off < 256; off <<= 1) {
        int tmp = (t >= off) ? lds[t - off] : 0;
        __syncthreads();
        lds[t] += tmp;
        __syncthreads();
    }
    int run = lds[t] - s;
#pragma unroll
    for (int k = 0; k < 4; ++k) {
        int i = base + k;
        if (i < n) ex[i] = run;
        run += v[k];
    }
    if (t == 255) bsum[b] = lds[255];
}

__global__ __launch_bounds__(128) void k_gscan2(int* bsum, int nblk) {
    __shared__ int lds[128];
    int t = threadIdx.x;
    int v = (t < nblk) ? bsum[t] : 0;
    lds[t] = v;
    __syncthreads();
    for (int off = 1; off < 128; off <<= 1) {
        int tmp = (t >= off) ? lds[t - off] : 0;
        __syncthreads();
        lds[t] += tmp;
        __syncthreads();
    }
    if (t < nblk) bsum[t] = lds[t] - v;  // exclusive
}

__global__ void k_gscan3(int* __restrict__ ex, const int* __restrict__ bsum, int n) {
    int i = blockIdx.x * blockDim.x + threadIdx.x;
    if (i < n) ex[i] += bsum[i >> 10];
}

// ---------------------------------------------------------------------------
// P3: partition edges into per-(block,bucket) contiguous runs (LDS cursors only)
__global__ __launch_bounds__(256) void k_part(const void* ei, const int* __restrict__ flag,
                                              const int* __restrict__ off,
                                              unsigned* __restrict__ packed) {
    __shared__ int cur[K_B];
    int b = blockIdx.x;
    for (int i = threadIdx.x; i < K_B; i += 256) cur[i] = off[i * B_P + b];
    __syncthreads();
    int is32 = *flag;
    int e0 = b * CH, e1 = min(e0 + CH, NE);
    for (int e = e0 + threadIdx.x; e < e1; e += 256) {
        int s, d;
        load_edge(ei, is32, e, s, d);
        int k = d >> 8;
        int pos = atomicAdd(&cur[k], 1);
        packed[pos] = ((unsigned)s << 8) | (unsigned)(d & 255);
    }
}

// ---------------------------------------------------------------------------
// P4 fused per-bucket: count -> local scan -> rowptr/dinv/xn -> place ssrc.
// Each bucket (256 nodes + its contiguous edge range) owned by exactly 1 block.
__global__ __launch_bounds__(256) void k_bucket(const int* __restrict__ off,
                                                const unsigned* __restrict__ packed,
                                                const float* __restrict__ x,
                                                int* __restrict__ rowptr,
                                                float* __restrict__ dinv,
                                                float2* __restrict__ xn,
                                                int* __restrict__ ssrc) {
    __shared__ int cnt[256];
    __shared__ int excl[256];
    int k = blockIdx.x, t = threadIdx.x;
    cnt[t] = 0;
    __syncthreads();
    int g0 = off[k * B_P];
    int g1 = (k == K_B - 1) ? NE : off[(k + 1) * B_P];
    for (int i = g0 + t; i < g1; i += 256)
        atomicAdd(&cnt[packed[i] & 255u], 1);
    __syncthreads();
    int v = cnt[t];
    excl[t] = v;
    __syncthreads();
    for (int o = 1; o < 256; o <<= 1) {
        int tmp = (t >= o) ? excl[t - o] : 0;
        __syncthreads();
        excl[t] += tmp;
        __syncthreads();
    }
    int rb = g0 + excl[t] - v;  // rowptr[n]: bucket start + local exclusive prefix
    int n = (k << 8) + t;
    if (n < NN) {
        rowptr[n] = rb;
        float di = rsqrtf((float)(v + 1));  // +1 self-loop
        dinv[n] = di;
        float2 xv = ((const float2*)x)[n];
        xn[n] = make_float2(xv.x * di, xv.y * di);
    }
    if (k == K_B - 1 && t == 0) rowptr[NN] = NE;
    __syncthreads();
    excl[t] = rb;   // reuse as row base for placement
    cnt[t] = 0;
    __syncthreads();
    for (int i = g0 + t; i < g1; i += 256) {
        unsigned pk = packed[i];
        int dl = pk & 255u;
        int r = atomicAdd(&cnt[dl], 1);
        ssrc[excl[dl] + r] = (int)(pk >> 8);
    }
}

// ---------------------------------------------------------------------------
// Layer 1 fused: agg of xn (2-wide) + 2->64 transform + bias + ReLU.
__global__ __launch_bounds__(256) void k_layer1(const int* __restrict__ rowptr,
                                                const int* __restrict__ ssrc,
                                                const float2* __restrict__ xn,
                                                const float* __restrict__ dinv,
                                                const float* __restrict__ W1,
                                                const float* __restrict__ b1,
                                                float* __restrict__ h) {
    int node = blockIdx.x * 4 + (threadIdx.x >> 6);
    if (node >= NN) return;
    int lane = threadIdx.x & 63;
    float2 a = xn[node];  // self loop
    float ax = a.x, ay = a.y;
    int s0 = rowptr[node], e0 = rowptr[node + 1];
    int i = s0;
    for (; i + 2 <= e0; i += 2) {
        float2 v0 = xn[ssrc[i]];
        float2 v1 = xn[ssrc[i + 1]];
        ax += v0.x + v1.x;
        ay += v0.y + v1.y;
    }
    for (; i < e0; ++i) { float2 v = xn[ssrc[i]]; ax += v.x; ay += v.y; }
    float di = dinv[node];
    ax *= di; ay *= di;
    float v = fmaf(ax, W1[lane], fmaf(ay, W1[64 + lane], b1[lane]));
    h[(size_t)node * 64 + lane] = fmaxf(v, 0.f);
}

// 64x64 GEMM transform: t[n][:] = dinv[n] * (h[n][:] @ W)
__global__ __launch_bounds__(256) void k_gemm64(const float* __restrict__ h,
                                                const float* __restrict__ W,
                                                const float* __restrict__ dinv,
                                                float* __restrict__ t) {
    __shared__ float Ws[64 * 64];
    __shared__ float hs[4][64];
    int tx = threadIdx.x & 63, ty = threadIdx.x >> 6;
    for (int i = threadIdx.x; i < 64 * 64; i += 256) Ws[i] = W[i];
    __syncthreads();
    int base = blockIdx.x * 64;
    for (int it = 0; it < 16; ++it) {
        int n = base + it * 4 + ty;
        if (n < NN) hs[ty][tx] = h[(size_t)n * 64 + tx];
        __syncthreads();
        if (n < NN) {
            float acc = 0.f;
#pragma unroll
            for (int k = 0; k < 64; ++k) acc += hs[ty][k] * Ws[k * 64 + tx];
            t[(size_t)n * 64 + tx] = dinv[n] * acc;
        }
        __syncthreads();
    }
}

// 64->1 transform: t3[n] = dinv[n] * dot(h[n][:], W3)
__global__ void k_transform3(const float* __restrict__ h, const float* __restrict__ W3,
                             const float* __restrict__ dinv, float* __restrict__ t3) {
    int tid = blockIdx.x * blockDim.x + threadIdx.x;
    if (tid >= NN * 64) return;
    int n = tid >> 6, k = tid & 63;
    float v = h[(size_t)n * 64 + k] * W3[k];
#pragma unroll
    for (int off = 32; off > 0; off >>= 1) v += __shfl_down(v, off, 64);
    if (k == 0) t3[n] = dinv[n] * v;
}

// ---------------------------------------------------------------------------
// Pull aggregation (64-wide), fused finalize: one 64-lane wave per node.
__global__ __launch_bounds__(256) void k_aggregate(const int* __restrict__ rowptr,
                                                   const int* __restrict__ ssrc,
                                                   const float* __restrict__ t,
                                                   const float* __restrict__ dinv,
                                                   const float* __restrict__ b,
                                                   float* __restrict__ hout, int relu) {
    int node = blockIdx.x * 4 + (threadIdx.x >> 6);
    if (node >= NN) return;
    int lane = threadIdx.x & 63;
    int start = rowptr[node], end = rowptr[node + 1];
    float acc = t[(size_t)node * 64 + lane];  // self loop
    int i = start;
    for (; i + 4 <= end; i += 4) {
        int s0 = ssrc[i], s1 = ssrc[i + 1], s2 = ssrc[i + 2], s3 = ssrc[i + 3];
        float a0 = t[(size_t)s0 * 64 + lane];
        float a1 = t[(size_t)s1 * 64 + lane];
        float a2 = t[(size_t)s2 * 64 + lane];
        float a3 = t[(size_t)s3 * 64 + lane];
        acc += a0 + a1 + a2 + a3;
    }
    for (; i < end; ++i) acc += t[(size_t)ssrc[i] * 64 + lane];
    float v = dinv[node] * acc + b[lane];
    if (relu) v = fmaxf(v, 0.f);
    hout[(size_t)node * 64 + lane] = v;
}

// Scalar variant for the 1-wide last layer: one thread per node.
__global__ void k_aggregate3(const int* __restrict__ rowptr, const int* __restrict__ ssrc,
                             const float* __restrict__ t3, const float* __restrict__ dinv,
                             const float* __restrict__ b3, float* __restrict__ out) {
    int n = blockIdx.x * blockDim.x + threadIdx.x;
    if (n >= NN) return;
    int s = rowptr[n], e = rowptr[n + 1];
    float acc = t3[n];
    int i = s;
    for (; i + 4 <= e; i += 4)
        acc += t3[ssrc[i]] + t3[ssrc[i + 1]] + t3[ssrc[i + 2]] + t3[ssrc[i + 3]];
    for (; i < e; ++i) acc += t3[ssrc[i]];
    out[n] = dinv[n] * acc + b3[0];
}

// ---------------------------------------------------------------------------
extern "C" void kernel_launch(void* const* d_in, const int* in_sizes, int n_in,
                              void* d_out, int out_size, void* d_ws, size_t ws_size,
                              hipStream_t stream) {
    const float* x  = (const float*)d_in[0];
    const void*  ei = d_in[1];
    const float* W1 = (const float*)d_in[2];
    const float* b1 = (const float*)d_in[3];
    const float* W2 = (const float*)d_in[4];
    const float* b2 = (const float*)d_in[5];
    const float* W3 = (const float*)d_in[6];
    const float* b3 = (const float*)d_in[7];
    float* out = (float*)d_out;

    char* ws = (char*)d_ws;
    size_t off_b = 0;
    auto take = [&](size_t bytes) -> char* {
        char* p = ws + off_b;
        off_b = (off_b + bytes + 255) & ~(size_t)255;
        return p;
    };
    float*    dinv   = (float*)take((size_t)NN * 4);
    int*      flag   = (int*)take(4);
    int*      bsum   = (int*)take(128 * 4);
    int*      rowptr = (int*)take((size_t)(NN + 1) * 4);
    int*      hist   = (int*)take((size_t)NSC * 4);
    int*      histS  = (int*)take((size_t)NSC * 4);
    unsigned* packed = (unsigned*)take((size_t)NE * 4);
    int*      ssrc   = (int*)take((size_t)NE * 4);
    float2*   xn     = (float2*)take((size_t)NN * 8);
    float*    tb     = (float*)take((size_t)NN * 64 * 4);
    float*    hb     = (float*)take((size_t)NN * 64 * 4);
    float*    t3     = (float*)take((size_t)NN * 4);

    // --- edge dtype detect ---
    hipMemsetAsync(flag, 0, 4, stream);
    k_detect<<<256, 256, 0, stream>>>((const unsigned int*)ei, flag);

    // --- atomic-free radix partition by dst (coarse buckets of 256 nodes) ---
    k_hist<<<B_P, 256, 0, stream>>>(ei, flag, hist);
    k_gscan1<<<NBLK_H, 256, 0, stream>>>(hist, histS, bsum, NSC);
    k_gscan2<<<1, 128, 0, stream>>>(bsum, NBLK_H);
    k_gscan3<<<(NSC + 255) / 256, 256, 0, stream>>>(histS, bsum, NSC);
    k_part<<<B_P, 256, 0, stream>>>(ei, flag, histS, packed);

    // --- fused per-bucket: count + scan -> rowptr/dinv/xn + place ssrc ---
    k_bucket<<<K_B, 256, 0, stream>>>(histS, packed, x, rowptr, dinv, xn, ssrc);

    const int nblk_agg = (NN + 3) / 4;  // 4 waves (nodes) per block
    const int nblk_nf  = (NN * 64 + 255) / 256;

    // --- layer 1 (fused 2-wide aggregate + transform) ---
    k_layer1<<<nblk_agg, 256, 0, stream>>>(rowptr, ssrc, xn, dinv, W1, b1, hb);

    // --- layer 2 ---
    k_gemm64<<<(NN + 63) / 64, 256, 0, stream>>>(hb, W2, dinv, tb);
    k_aggregate<<<nblk_agg, 256, 0, stream>>>(rowptr, ssrc, tb, dinv, b2, hb, 1);

    // --- layer 3 ---
    k_transform3<<<nblk_nf, 256, 0, stream>>>(hb, W3, dinv, t3);
    k_aggregate3<<<(NN + 255) / 256, 256, 0, stream>>>(rowptr, ssrc, t3, dinv, b3, out);
}

// Round 6
// 204.032 us; speedup vs baseline: 2.3532x; 1.4005x over previous
//
#include <hip/hip_runtime.h>

#define NN 100000
#define NE 1600000

// Radix partition params: buckets of 256 nodes
#define K_B 391                          // ceil(NN/256) buckets
#define B_P 256                          // partition blocks
#define CH  ((NE + B_P - 1) / B_P)       // 6250 edges per partition block
#define NSC (K_B * B_P)                  // histogram table size (100096)
#define NBLK_H ((NSC + 1023) / 1024)     // 98 blocks for hist scan

// ---------------------------------------------------------------------------
// edge_index dtype detection: if int64 (values < 2^31), odd 32-bit words are 0.
__global__ void k_detect(const unsigned int* w, int* flag) {
    int i = blockIdx.x * blockDim.x + threadIdx.x;
    if (i < 65536 && w[2 * i + 1] != 0u) *flag = 1;
}

__device__ __forceinline__ void load_edge(const void* ei, int is32, int e,
                                          int& s, int& d) {
    if (is32) {
        const int* p = (const int*)ei;
        s = p[e]; d = p[NE + e];
    } else {
        const long long* p = (const long long*)ei;
        s = (int)p[e]; d = (int)p[NE + e];
    }
}

// ---------------------------------------------------------------------------
// P1: per-block histogram of dst>>8 over this block's edge chunk
__global__ __launch_bounds__(256) void k_hist(const void* ei, const int* __restrict__ flag,
                                              int* __restrict__ hist) {
    __shared__ int h[K_B];
    for (int i = threadIdx.x; i < K_B; i += 256) h[i] = 0;
    __syncthreads();
    int b = blockIdx.x;
    int is32 = *flag;
    int e0 = b * CH, e1 = min(e0 + CH, NE);
    for (int e = e0 + threadIdx.x; e < e1; e += 256) {
        int d = is32 ? ((const int*)ei)[NE + e] : (int)((const long long*)ei)[NE + e];
        atomicAdd(&h[d >> 8], 1);
    }
    __syncthreads();
    for (int i = threadIdx.x; i < K_B; i += 256) hist[i * B_P + b] = h[i];
}

// ---------------------------------------------------------------------------
// Generalized hierarchical exclusive scan (3 kernels), n <= 128*1024
__global__ __launch_bounds__(256) void k_gscan1(const int* __restrict__ in,
                                                int* __restrict__ ex,
                                                int* __restrict__ bsum, int n) {
    __shared__ int lds[256];
    int b = blockIdx.x, t = threadIdx.x;
    int base = b * 1024 + t * 4;
    int v[4];
#pragma unroll
    for (int k = 0; k < 4; ++k) { int i = base + k; v[k] = (i < n) ? in[i] : 0; }
    int s = v[0] + v[1] + v[2] + v[3];
    lds[t] = s;
    __syncthreads();
    for (int off = 1; off < 256; off <<= 1) {
        int tmp = (t >= off) ? lds[t - off] : 0;
        __syncthreads();
        lds[t] += tmp;
        __syncthreads();
    }
    int run = lds[t] - s;
#pragma unroll
    for (int k = 0; k < 4; ++k) {
        int i = base + k;
        if (i < n) ex[i] = run;
        run += v[k];
    }
    if (t == 255) bsum[b] = lds[255];
}

__global__ __launch_bounds__(128) void k_gscan2(int* bsum, int nblk) {
    __shared__ int lds[128];
    int t = threadIdx.x;
    int v = (t < nblk) ? bsum[t] : 0;
    lds[t] = v;
    __syncthreads();
    for (int off = 1; off < 128; off <<= 1) {
        int tmp = (t >= off) ? lds[t - off] : 0;
        __syncthreads();
        lds[t] += tmp;
        __syncthreads();
    }
    if (t < nblk) bsum[t] = lds[t] - v;  // exclusive
}

__global__ void k_gscan3(int* __restrict__ ex, const int* __restrict__ bsum, int n) {
    int i = blockIdx.x * blockDim.x + threadIdx.x;
    if (i < n) ex[i] += bsum[i >> 10];
}

// ---------------------------------------------------------------------------
// P3: partition edges into per-(block,bucket) contiguous runs (LDS cursors only)
__global__ __launch_bounds__(256) void k_part(const void* ei, const int* __restrict__ flag,
                                              const int* __restrict__ off,
                                              unsigned* __restrict__ packed) {
    __shared__ int cur[K_B];
    int b = blockIdx.x;
    for (int i = threadIdx.x; i < K_B; i += 256) cur[i] = off[i * B_P + b];
    __syncthreads();
    int is32 = *flag;
    int e0 = b * CH, e1 = min(e0 + CH, NE);
    for (int e = e0 + threadIdx.x; e < e1; e += 256) {
        int s, d;
        load_edge(ei, is32, e, s, d);
        int k = d >> 8;
        int pos = atomicAdd(&cur[k], 1);
        packed[pos] = ((unsigned)s << 8) | (unsigned)(d & 255);
    }
}

// ---------------------------------------------------------------------------
// P4 fused per-bucket: count -> local scan -> rowptr/dinv/xn -> place ssrc.
__global__ __launch_bounds__(256) void k_bucket(const int* __restrict__ off,
                                                const unsigned* __restrict__ packed,
                                                const float* __restrict__ x,
                                                int* __restrict__ rowptr,
                                                float* __restrict__ dinv,
                                                float2* __restrict__ xn,
                                                int* __restrict__ ssrc) {
    __shared__ int cnt[256];
    __shared__ int excl[256];
    int k = blockIdx.x, t = threadIdx.x;
    cnt[t] = 0;
    __syncthreads();
    int g0 = off[k * B_P];
    int g1 = (k == K_B - 1) ? NE : off[(k + 1) * B_P];
    for (int i = g0 + t; i < g1; i += 256)
        atomicAdd(&cnt[packed[i] & 255u], 1);
    __syncthreads();
    int v = cnt[t];
    excl[t] = v;
    __syncthreads();
    for (int o = 1; o < 256; o <<= 1) {
        int tmp = (t >= o) ? excl[t - o] : 0;
        __syncthreads();
        excl[t] += tmp;
        __syncthreads();
    }
    int rb = g0 + excl[t] - v;  // rowptr[n]: bucket start + local exclusive prefix
    int n = (k << 8) + t;
    if (n < NN) {
        rowptr[n] = rb;
        float di = rsqrtf((float)(v + 1));  // +1 self-loop
        dinv[n] = di;
        float2 xv = ((const float2*)x)[n];
        xn[n] = make_float2(xv.x * di, xv.y * di);
    }
    if (k == K_B - 1 && t == 0) rowptr[NN] = NE;
    __syncthreads();
    excl[t] = rb;   // reuse as row base for placement
    cnt[t] = 0;
    __syncthreads();
    for (int i = g0 + t; i < g1; i += 256) {
        unsigned pk = packed[i];
        int dl = pk & 255u;
        int r = atomicAdd(&cnt[dl], 1);
        ssrc[excl[dl] + r] = (int)(pk >> 8);
    }
}

// ---------------------------------------------------------------------------
// Layer 1 fused: lane-parallel agg of xn (2-wide) + 2->64 transform + bias +
// ReLU + next-layer dinv scale.  hn1[n][j] = dinv[n]*relu(...)
__global__ __launch_bounds__(256) void k_layer1(const int* __restrict__ rowptr,
                                                const int* __restrict__ ssrc,
                                                const float2* __restrict__ xn,
                                                const float* __restrict__ dinv,
                                                const float* __restrict__ W1,
                                                const float* __restrict__ b1,
                                                float* __restrict__ hn1) {
    int node = blockIdx.x * 4 + (threadIdx.x >> 6);
    if (node >= NN) return;
    int lane = threadIdx.x & 63;
    int s0 = rowptr[node], e0 = rowptr[node + 1];
    float ax = 0.f, ay = 0.f;
    for (int i = s0 + lane; i < e0; i += 64) {
        float2 v = xn[ssrc[i]];
        ax += v.x; ay += v.y;
    }
#pragma unroll
    for (int m = 1; m < 64; m <<= 1) {
        ax += __shfl_xor(ax, m, 64);
        ay += __shfl_xor(ay, m, 64);
    }
    float2 a = xn[node];  // self loop
    ax += a.x; ay += a.y;
    float di = dinv[node];
    ax *= di; ay *= di;
    float v = fmaf(ax, W1[lane], fmaf(ay, W1[64 + lane], b1[lane]));
    hn1[(size_t)node * 64 + lane] = di * fmaxf(v, 0.f);
}

// ---------------------------------------------------------------------------
// Layer 2 fused: 64-wide aggregate of hn1 + 64x64 GEMM (W2 in LDS) + bias +
// ReLU + next-layer dinv scale.  hn2 = dinv*relu(dinv*(g@W2)+b2)
__global__ __launch_bounds__(256) void k_layer2(const int* __restrict__ rowptr,
                                                const int* __restrict__ ssrc,
                                                const float* __restrict__ hn1,
                                                const float* __restrict__ dinv,
                                                const float* __restrict__ W2,
                                                const float* __restrict__ b2,
                                                float* __restrict__ hn2) {
    __shared__ float Ws[64 * 64];
    __shared__ float gs[4][64];
    for (int i = threadIdx.x; i < 64 * 64; i += 256) Ws[i] = W2[i];
    __syncthreads();
    int node = blockIdx.x * 4 + (threadIdx.x >> 6);
    if (node >= NN) return;
    int w = threadIdx.x >> 6, lane = threadIdx.x & 63;
    int start = rowptr[node], end = rowptr[node + 1];
    float acc = hn1[(size_t)node * 64 + lane];  // self loop
    int i = start;
    for (; i + 4 <= end; i += 4) {
        int s0 = ssrc[i], s1 = ssrc[i + 1], s2 = ssrc[i + 2], s3 = ssrc[i + 3];
        float a0 = hn1[(size_t)s0 * 64 + lane];
        float a1 = hn1[(size_t)s1 * 64 + lane];
        float a2 = hn1[(size_t)s2 * 64 + lane];
        float a3 = hn1[(size_t)s3 * 64 + lane];
        acc += a0 + a1 + a2 + a3;
    }
    for (; i < end; ++i) acc += hn1[(size_t)ssrc[i] * 64 + lane];
    gs[w][lane] = acc;   // wave-synchronous LDS use (same wave writes+reads)
    float o = 0.f;
#pragma unroll
    for (int k = 0; k < 64; ++k) o = fmaf(gs[w][k], Ws[k * 64 + lane], o);
    float di = dinv[node];
    float v = fmaf(di, o, b2[lane]);
    hn2[(size_t)node * 64 + lane] = di * fmaxf(v, 0.f);
}

// 64->1 transform: t3[n] = dot(hn2[n][:], W3)   (dinv already folded into hn2)
__global__ void k_transform3(const float* __restrict__ hn2, const float* __restrict__ W3,
                             float* __restrict__ t3) {
    int tid = blockIdx.x * blockDim.x + threadIdx.x;
    if (tid >= NN * 64) return;
    int n = tid >> 6, k = tid & 63;
    float v = hn2[(size_t)n * 64 + k] * W3[k];
#pragma unroll
    for (int off = 32; off > 0; off >>= 1) v += __shfl_down(v, off, 64);
    if (k == 0) t3[n] = v;
}

// Scalar last layer: out[n] = dinv[n]*(t3[n] + sum t3[src]) + b3
__global__ void k_aggregate3(const int* __restrict__ rowptr, const int* __restrict__ ssrc,
                             const float* __restrict__ t3, const float* __restrict__ dinv,
                             const float* __restrict__ b3, float* __restrict__ out) {
    int n = blockIdx.x * blockDim.x + threadIdx.x;
    if (n >= NN) return;
    int s = rowptr[n], e = rowptr[n + 1];
    float acc = t3[n];
    int i = s;
    for (; i + 4 <= e; i += 4)
        acc += t3[ssrc[i]] + t3[ssrc[i + 1]] + t3[ssrc[i + 2]] + t3[ssrc[i + 3]];
    for (; i < e; ++i) acc += t3[ssrc[i]];
    out[n] = dinv[n] * acc + b3[0];
}

// ---------------------------------------------------------------------------
extern "C" void kernel_launch(void* const* d_in, const int* in_sizes, int n_in,
                              void* d_out, int out_size, void* d_ws, size_t ws_size,
                              hipStream_t stream) {
    const float* x  = (const float*)d_in[0];
    const void*  ei = d_in[1];
    const float* W1 = (const float*)d_in[2];
    const float* b1 = (const float*)d_in[3];
    const float* W2 = (const float*)d_in[4];
    const float* b2 = (const float*)d_in[5];
    const float* W3 = (const float*)d_in[6];
    const float* b3 = (const float*)d_in[7];
    float* out = (float*)d_out;

    char* ws = (char*)d_ws;
    size_t off_b = 0;
    auto take = [&](size_t bytes) -> char* {
        char* p = ws + off_b;
        off_b = (off_b + bytes + 255) & ~(size_t)255;
        return p;
    };
    float*    dinv   = (float*)take((size_t)NN * 4);
    int*      flag   = (int*)take(4);
    int*      bsum   = (int*)take(128 * 4);
    int*      rowptr = (int*)take((size_t)(NN + 1) * 4);
    int*      hist   = (int*)take((size_t)NSC * 4);
    int*      histS  = (int*)take((size_t)NSC * 4);
    unsigned* packed = (unsigned*)take((size_t)NE * 4);
    int*      ssrc   = (int*)take((size_t)NE * 4);
    float2*   xn     = (float2*)take((size_t)NN * 8);
    float*    hn1    = (float*)take((size_t)NN * 64 * 4);
    float*    hn2    = (float*)take((size_t)NN * 64 * 4);
    float*    t3     = (float*)take((size_t)NN * 4);

    // --- edge dtype detect ---
    hipMemsetAsync(flag, 0, 4, stream);
    k_detect<<<256, 256, 0, stream>>>((const unsigned int*)ei, flag);

    // --- atomic-free radix partition by dst (coarse buckets of 256 nodes) ---
    k_hist<<<B_P, 256, 0, stream>>>(ei, flag, hist);
    k_gscan1<<<NBLK_H, 256, 0, stream>>>(hist, histS, bsum, NSC);
    k_gscan2<<<1, 128, 0, stream>>>(bsum, NBLK_H);
    k_gscan3<<<(NSC + 255) / 256, 256, 0, stream>>>(histS, bsum, NSC);
    k_part<<<B_P, 256, 0, stream>>>(ei, flag, histS, packed);

    // --- fused per-bucket: count + scan -> rowptr/dinv/xn + place ssrc ---
    k_bucket<<<K_B, 256, 0, stream>>>(histS, packed, x, rowptr, dinv, xn, ssrc);

    const int nblk_agg = (NN + 3) / 4;  // 4 waves (nodes) per block
    const int nblk_nf  = (NN * 64 + 255) / 256;

    // --- layer 1 (lane-parallel 2-wide aggregate + transform) ---
    k_layer1<<<nblk_agg, 256, 0, stream>>>(rowptr, ssrc, xn, dinv, W1, b1, hn1);

    // --- layer 2 (fused aggregate + GEMM) ---
    k_layer2<<<nblk_agg, 256, 0, stream>>>(rowptr, ssrc, hn1, dinv, W2, b2, hn2);

    // --- layer 3 ---
    k_transform3<<<nblk_nf, 256, 0, stream>>>(hn2, W3, t3);
    k_aggregate3<<<(NN + 255) / 256, 256, 0, stream>>>(rowptr, ssrc, t3, dinv, b3, out);
}

// Round 7
// 188.297 us; speedup vs baseline: 2.5498x; 1.0836x over previous
//
#include <hip/hip_runtime.h>
#include <hip/hip_fp16.h>

#define NN 100000
#define NE 1600000

// Radix partition params: buckets of 256 nodes
#define K_B 391                          // ceil(NN/256) buckets
#define B_P 256                          // partition blocks
#define CH  ((NE + B_P - 1) / B_P)       // 6250 edges per partition block
#define NSC (K_B * B_P)                  // histogram table size (100096)
#define NBLK_H ((NSC + 1023) / 1024)     // 98 blocks for hist scan

// ---------------------------------------------------------------------------
// edge_index dtype detection: if int64 (values < 2^31), odd 32-bit words are 0.
__global__ void k_detect(const unsigned int* w, int* flag) {
    int i = blockIdx.x * blockDim.x + threadIdx.x;
    if (i < 65536 && w[2 * i + 1] != 0u) *flag = 1;
}

__device__ __forceinline__ void load_edge(const void* ei, int is32, int e,
                                          int& s, int& d) {
    if (is32) {
        const int* p = (const int*)ei;
        s = p[e]; d = p[NE + e];
    } else {
        const long long* p = (const long long*)ei;
        s = (int)p[e]; d = (int)p[NE + e];
    }
}

// ---------------------------------------------------------------------------
// P1: per-block histogram of dst>>8 over this block's edge chunk
__global__ __launch_bounds__(256) void k_hist(const void* ei, const int* __restrict__ flag,
                                              int* __restrict__ hist) {
    __shared__ int h[K_B];
    for (int i = threadIdx.x; i < K_B; i += 256) h[i] = 0;
    __syncthreads();
    int b = blockIdx.x;
    int is32 = *flag;
    int e0 = b * CH, e1 = min(e0 + CH, NE);
    for (int e = e0 + threadIdx.x; e < e1; e += 256) {
        int d = is32 ? ((const int*)ei)[NE + e] : (int)((const long long*)ei)[NE + e];
        atomicAdd(&h[d >> 8], 1);
    }
    __syncthreads();
    for (int i = threadIdx.x; i < K_B; i += 256) hist[i * B_P + b] = h[i];
}

// ---------------------------------------------------------------------------
// Generalized hierarchical exclusive scan (3 kernels), n <= 128*1024
__global__ __launch_bounds__(256) void k_gscan1(const int* __restrict__ in,
                                                int* __restrict__ ex,
                                                int* __restrict__ bsum, int n) {
    __shared__ int lds[256];
    int b = blockIdx.x, t = threadIdx.x;
    int base = b * 1024 + t * 4;
    int v[4];
#pragma unroll
    for (int k = 0; k < 4; ++k) { int i = base + k; v[k] = (i < n) ? in[i] : 0; }
    int s = v[0] + v[1] + v[2] + v[3];
    lds[t] = s;
    __syncthreads();
    for (int off = 1; off < 256; off <<= 1) {
        int tmp = (t >= off) ? lds[t - off] : 0;
        __syncthreads();
        lds[t] += tmp;
        __syncthreads();
    }
    int run = lds[t] - s;
#pragma unroll
    for (int k = 0; k < 4; ++k) {
        int i = base + k;
        if (i < n) ex[i] = run;
        run += v[k];
    }
    if (t == 255) bsum[b] = lds[255];
}

__global__ __launch_bounds__(128) void k_gscan2(int* bsum, int nblk) {
    __shared__ int lds[128];
    int t = threadIdx.x;
    int v = (t < nblk) ? bsum[t] : 0;
    lds[t] = v;
    __syncthreads();
    for (int off = 1; off < 128; off <<= 1) {
        int tmp = (t >= off) ? lds[t - off] : 0;
        __syncthreads();
        lds[t] += tmp;
        __syncthreads();
    }
    if (t < nblk) bsum[t] = lds[t] - v;  // exclusive
}

__global__ void k_gscan3(int* __restrict__ ex, const int* __restrict__ bsum, int n) {
    int i = blockIdx.x * blockDim.x + threadIdx.x;
    if (i < n) ex[i] += bsum[i >> 10];
}

// ---------------------------------------------------------------------------
// P3: partition edges into per-(block,bucket) contiguous runs (LDS cursors only)
__global__ __launch_bounds__(256) void k_part(const void* ei, const int* __restrict__ flag,
                                              const int* __restrict__ off,
                                              unsigned* __restrict__ packed) {
    __shared__ int cur[K_B];
    int b = blockIdx.x;
    for (int i = threadIdx.x; i < K_B; i += 256) cur[i] = off[i * B_P + b];
    __syncthreads();
    int is32 = *flag;
    int e0 = b * CH, e1 = min(e0 + CH, NE);
    for (int e = e0 + threadIdx.x; e < e1; e += 256) {
        int s, d;
        load_edge(ei, is32, e, s, d);
        int k = d >> 8;
        int pos = atomicAdd(&cur[k], 1);
        packed[pos] = ((unsigned)s << 8) | (unsigned)(d & 255);
    }
}

// ---------------------------------------------------------------------------
// P4 fused per-bucket: count -> local scan -> rowptr/dinv/xn -> place ssrc.
__global__ __launch_bounds__(256) void k_bucket(const int* __restrict__ off,
                                                const unsigned* __restrict__ packed,
                                                const float* __restrict__ x,
                                                int* __restrict__ rowptr,
                                                float* __restrict__ dinv,
                                                float2* __restrict__ xn,
                                                int* __restrict__ ssrc) {
    __shared__ int cnt[256];
    __shared__ int excl[256];
    int k = blockIdx.x, t = threadIdx.x;
    cnt[t] = 0;
    __syncthreads();
    int g0 = off[k * B_P];
    int g1 = (k == K_B - 1) ? NE : off[(k + 1) * B_P];
    for (int i = g0 + t; i < g1; i += 256)
        atomicAdd(&cnt[packed[i] & 255u], 1);
    __syncthreads();
    int v = cnt[t];
    excl[t] = v;
    __syncthreads();
    for (int o = 1; o < 256; o <<= 1) {
        int tmp = (t >= o) ? excl[t - o] : 0;
        __syncthreads();
        excl[t] += tmp;
        __syncthreads();
    }
    int rb = g0 + excl[t] - v;  // rowptr[n]: bucket start + local exclusive prefix
    int n = (k << 8) + t;
    if (n < NN) {
        rowptr[n] = rb;
        float di = rsqrtf((float)(v + 1));  // +1 self-loop
        dinv[n] = di;
        float2 xv = ((const float2*)x)[n];
        xn[n] = make_float2(xv.x * di, xv.y * di);
    }
    if (k == K_B - 1 && t == 0) rowptr[NN] = NE;
    __syncthreads();
    excl[t] = rb;   // reuse as row base for placement
    cnt[t] = 0;
    __syncthreads();
    for (int i = g0 + t; i < g1; i += 256) {
        unsigned pk = packed[i];
        int dl = pk & 255u;
        int r = atomicAdd(&cnt[dl], 1);
        ssrc[excl[dl] + r] = (int)(pk >> 8);
    }
}

// ---------------------------------------------------------------------------
// Layer 1 fused: lane-parallel agg of xn (2-wide) + 2->64 transform + bias +
// ReLU + next-layer dinv scale.  hn1[n][j] = fp16( dinv[n]*relu(...) )
__global__ __launch_bounds__(256) void k_layer1(const int* __restrict__ rowptr,
                                                const int* __restrict__ ssrc,
                                                const float2* __restrict__ xn,
                                                const float* __restrict__ dinv,
                                                const float* __restrict__ W1,
                                                const float* __restrict__ b1,
                                                __half* __restrict__ hn1) {
    int node = blockIdx.x * 4 + (threadIdx.x >> 6);
    if (node >= NN) return;
    int lane = threadIdx.x & 63;
    int s0 = rowptr[node], e0 = rowptr[node + 1];
    float ax = 0.f, ay = 0.f;
    for (int i = s0 + lane; i < e0; i += 64) {
        float2 v = xn[ssrc[i]];
        ax += v.x; ay += v.y;
    }
#pragma unroll
    for (int m = 1; m < 64; m <<= 1) {
        ax += __shfl_xor(ax, m, 64);
        ay += __shfl_xor(ay, m, 64);
    }
    float2 a = xn[node];  // self loop
    ax += a.x; ay += a.y;
    float di = dinv[node];
    ax *= di; ay *= di;
    float v = fmaf(ax, W1[lane], fmaf(ay, W1[64 + lane], b1[lane]));
    hn1[(size_t)node * 64 + lane] = __float2half(di * fmaxf(v, 0.f));
}

// ---------------------------------------------------------------------------
// Layer 2+3a fused: 64-wide fp16 aggregate of hn1 + 64x64 GEMM (W2 in LDS) +
// bias + ReLU + dinv scale + dot with W3 -> t3[n].  hn2 never hits global.
__global__ __launch_bounds__(256) void k_layer2(const int* __restrict__ rowptr,
                                                const int* __restrict__ ssrc,
                                                const __half* __restrict__ hn1,
                                                const float* __restrict__ dinv,
                                                const float* __restrict__ W2,
                                                const float* __restrict__ b2,
                                                const float* __restrict__ W3,
                                                float* __restrict__ t3) {
    __shared__ float Ws[64 * 64];
    __shared__ float gs[4][64];
    for (int i = threadIdx.x; i < 64 * 64; i += 256) Ws[i] = W2[i];
    __syncthreads();
    int node = blockIdx.x * 4 + (threadIdx.x >> 6);
    if (node >= NN) return;
    int w = threadIdx.x >> 6, lane = threadIdx.x & 63;
    int start = rowptr[node], end = rowptr[node + 1];
    float acc = __half2float(hn1[(size_t)node * 64 + lane]);  // self loop
    int i = start;
    for (; i + 4 <= end; i += 4) {
        int s0 = ssrc[i], s1 = ssrc[i + 1], s2 = ssrc[i + 2], s3 = ssrc[i + 3];
        float a0 = __half2float(hn1[(size_t)s0 * 64 + lane]);
        float a1 = __half2float(hn1[(size_t)s1 * 64 + lane]);
        float a2 = __half2float(hn1[(size_t)s2 * 64 + lane]);
        float a3 = __half2float(hn1[(size_t)s3 * 64 + lane]);
        acc += a0 + a1 + a2 + a3;
    }
    for (; i < end; ++i) acc += __half2float(hn1[(size_t)ssrc[i] * 64 + lane]);
    gs[w][lane] = acc;   // wave-synchronous LDS use (same wave writes+reads)
    float o = 0.f;
#pragma unroll
    for (int k = 0; k < 64; ++k) o = fmaf(gs[w][k], Ws[k * 64 + lane], o);
    float di = dinv[node];
    float v = fmaf(di, o, b2[lane]);
    float r = di * fmaxf(v, 0.f) * W3[lane];   // hn2 element * W3, then reduce
#pragma unroll
    for (int m = 1; m < 64; m <<= 1) r += __shfl_xor(r, m, 64);
    if (lane == 0) t3[node] = r;
}

// Scalar last layer: out[n] = dinv[n]*(t3[n] + sum t3[src]) + b3
__global__ void k_aggregate3(const int* __restrict__ rowptr, const int* __restrict__ ssrc,
                             const float* __restrict__ t3, const float* __restrict__ dinv,
                             const float* __restrict__ b3, float* __restrict__ out) {
    int n = blockIdx.x * blockDim.x + threadIdx.x;
    if (n >= NN) return;
    int s = rowptr[n], e = rowptr[n + 1];
    float acc = t3[n];
    int i = s;
    for (; i + 4 <= e; i += 4)
        acc += t3[ssrc[i]] + t3[ssrc[i + 1]] + t3[ssrc[i + 2]] + t3[ssrc[i + 3]];
    for (; i < e; ++i) acc += t3[ssrc[i]];
    out[n] = dinv[n] * acc + b3[0];
}

// ---------------------------------------------------------------------------
extern "C" void kernel_launch(void* const* d_in, const int* in_sizes, int n_in,
                              void* d_out, int out_size, void* d_ws, size_t ws_size,
                              hipStream_t stream) {
    const float* x  = (const float*)d_in[0];
    const void*  ei = d_in[1];
    const float* W1 = (const float*)d_in[2];
    const float* b1 = (const float*)d_in[3];
    const float* W2 = (const float*)d_in[4];
    const float* b2 = (const float*)d_in[5];
    const float* W3 = (const float*)d_in[6];
    const float* b3 = (const float*)d_in[7];
    float* out = (float*)d_out;

    char* ws = (char*)d_ws;
    size_t off_b = 0;
    auto take = [&](size_t bytes) -> char* {
        char* p = ws + off_b;
        off_b = (off_b + bytes + 255) & ~(size_t)255;
        return p;
    };
    float*    dinv   = (float*)take((size_t)NN * 4);
    int*      flag   = (int*)take(4);
    int*      bsum   = (int*)take(128 * 4);
    int*      rowptr = (int*)take((size_t)(NN + 1) * 4);
    int*      hist   = (int*)take((size_t)NSC * 4);
    int*      histS  = (int*)take((size_t)NSC * 4);
    unsigned* packed = (unsigned*)take((size_t)NE * 4);
    int*      ssrc   = (int*)take((size_t)NE * 4);
    float2*   xn     = (float2*)take((size_t)NN * 8);
    __half*   hn1    = (__half*)take((size_t)NN * 64 * 2);
    float*    t3     = (float*)take((size_t)NN * 4);

    // --- edge dtype detect ---
    hipMemsetAsync(flag, 0, 4, stream);
    k_detect<<<256, 256, 0, stream>>>((const unsigned int*)ei, flag);

    // --- atomic-free radix partition by dst (coarse buckets of 256 nodes) ---
    k_hist<<<B_P, 256, 0, stream>>>(ei, flag, hist);
    k_gscan1<<<NBLK_H, 256, 0, stream>>>(hist, histS, bsum, NSC);
    k_gscan2<<<1, 128, 0, stream>>>(bsum, NBLK_H);
    k_gscan3<<<(NSC + 255) / 256, 256, 0, stream>>>(histS, bsum, NSC);
    k_part<<<B_P, 256, 0, stream>>>(ei, flag, histS, packed);

    // --- fused per-bucket: count + scan -> rowptr/dinv/xn + place ssrc ---
    k_bucket<<<K_B, 256, 0, stream>>>(histS, packed, x, rowptr, dinv, xn, ssrc);

    const int nblk_agg = (NN + 3) / 4;  // 4 waves (nodes) per block

    // --- layer 1 (lane-parallel 2-wide aggregate + transform, fp16 out) ---
    k_layer1<<<nblk_agg, 256, 0, stream>>>(rowptr, ssrc, xn, dinv, W1, b1, hn1);

    // --- layer 2 + 3a (fused aggregate + GEMM + W3 dot) ---
    k_layer2<<<nblk_agg, 256, 0, stream>>>(rowptr, ssrc, hn1, dinv, W2, b2, W3, t3);

    // --- layer 3b (scalar aggregate) ---
    k_aggregate3<<<(NN + 255) / 256, 256, 0, stream>>>(rowptr, ssrc, t3, dinv, b3, out);
}